// Round 3
// baseline (357.065 us; speedup 1.0000x reference)
//
#include <hip/hip_runtime.h>
#include <math.h>

// B=2, S=2048, H=2048, NH=16, KVH=4, D=128, layer 5.
// GEMMs on mfma_f32_16x16x32_bf16; attention on mfma_f32_32x32x16_bf16.
// valid logit = qk / sqrt(128); masked logit = -65504*6 (finite, exp -> 0).

#define RSQ128 0.08838834764831845f
#define MASK6  (-393024.0f)

typedef __attribute__((ext_vector_type(8))) short short8;    // 8 bf16 = 4 VGPR
typedef __attribute__((ext_vector_type(4))) float f32x4;     // 16x16 C/D
typedef __attribute__((ext_vector_type(16))) float f32x16;   // 32x32 C/D

static __device__ __forceinline__ unsigned short f2bf(float x) {
    union { float f; unsigned u; } v; v.f = x;
    unsigned r = v.u + 0x7FFFu + ((v.u >> 16) & 1u);   // RNE
    return (unsigned short)(r >> 16);
}

static __device__ __forceinline__ void gl_lds16(const void* g, void* l) {
    __builtin_amdgcn_global_load_lds(
        (const __attribute__((address_space(1))) void*)g,
        (__attribute__((address_space(3))) void*)l, 16, 0, 0);
}

// ---------------------------------------------------------------------------
// fp32 -> bf16 convert, 8 elems/thread
// ---------------------------------------------------------------------------
__global__ void cvt_bf16(const float* __restrict__ in, unsigned short* __restrict__ out) {
    const int i = (blockIdx.x * 256 + threadIdx.x) * 8;
    const float4 a = *(const float4*)(in + i);
    const float4 b = *(const float4*)(in + i + 4);
    short8 o;
    o[0] = (short)f2bf(a.x); o[1] = (short)f2bf(a.y);
    o[2] = (short)f2bf(a.z); o[3] = (short)f2bf(a.w);
    o[4] = (short)f2bf(b.x); o[5] = (short)f2bf(b.y);
    o[6] = (short)f2bf(b.z); o[7] = (short)f2bf(b.w);
    *(short8*)(out + i) = o;
}

// ---------------------------------------------------------------------------
// V [8][2048][128] fp32 -> Vt [8][128][2048] bf16 (per (b,kvh) transpose)
// ---------------------------------------------------------------------------
__global__ void vtrans_bf16(const float* __restrict__ V, unsigned short* __restrict__ Vt) {
    __shared__ float Ts[64][65];
    const int t = threadIdx.x;
    const int s0 = blockIdx.x * 64, d0 = blockIdx.y * 64;
    const float* src = V + (size_t)blockIdx.z * 2048 * 128;
    unsigned short* dst = Vt + (size_t)blockIdx.z * 128 * 2048;
#pragma unroll
    for (int p = 0; p < 4; ++p) {
        const int f = p * 256 + t, r = f >> 4, cq = f & 15;
        const float4 v = *(const float4*)(src + (size_t)(s0 + r) * 128 + d0 + cq * 4);
        Ts[r][cq * 4 + 0] = v.x; Ts[r][cq * 4 + 1] = v.y;
        Ts[r][cq * 4 + 2] = v.z; Ts[r][cq * 4 + 3] = v.w;
    }
    __syncthreads();
#pragma unroll
    for (int p = 0; p < 2; ++p) {
        const int f = p * 256 + t, dr = f >> 3, c = f & 7;
        short8 o;
#pragma unroll
        for (int j = 0; j < 8; ++j) o[j] = (short)f2bf(Ts[c * 8 + j][dr]);
        *(short8*)(dst + (size_t)(d0 + dr) * 2048 + s0 + c * 8) = o;
    }
}

// ---------------------------------------------------------------------------
// NT GEMM bf16 MFMA (unchanged from R2 — known good)
// ---------------------------------------------------------------------------
template <bool BF16OUT>
__global__ __launch_bounds__(256, 2) void gemm_nt_mfma(
    const unsigned short* __restrict__ A,
    const unsigned short* __restrict__ W,
    const float* __restrict__ bias,
    void* __restrict__ Cout, int M, int N, int K)
{
    __shared__ __align__(16) unsigned short As[128 * 32];
    __shared__ __align__(16) unsigned short Ws[128 * 32];
    const int tid = threadIdx.x, lane = tid & 63, w = tid >> 6;
    const int wm = w & 1, wn = w >> 1;
    const int m0 = blockIdx.y * 128, n0 = blockIdx.x * 128;
    const int r0 = tid >> 2, c0 = tid & 3;

    const unsigned short* Ag = A + (size_t)(m0 + r0) * K + c0 * 8;
    const unsigned short* Wg = W + (size_t)(n0 + r0) * K + c0 * 8;

    f32x4 acc[4][4];
#pragma unroll
    for (int i = 0; i < 4; ++i)
#pragma unroll
        for (int j = 0; j < 4; ++j) acc[i][j] = (f32x4){0.f, 0.f, 0.f, 0.f};

    const int lm = lane & 15, lk = (lane >> 4) * 8;

    for (int k0 = 0; k0 < K; k0 += 32) {
        __syncthreads();
        gl_lds16(Ag + k0,                  As + tid * 8);
        gl_lds16(Ag + (size_t)64 * K + k0, As + (tid + 256) * 8);
        gl_lds16(Wg + k0,                  Ws + tid * 8);
        gl_lds16(Wg + (size_t)64 * K + k0, Ws + (tid + 256) * 8);
        __syncthreads();

        short8 a[4], b[4];
#pragma unroll
        for (int i = 0; i < 4; ++i)
            a[i] = *(const short8*)&As[(64 * wm + 16 * i + lm) * 32 + lk];
#pragma unroll
        for (int j = 0; j < 4; ++j)
            b[j] = *(const short8*)&Ws[(64 * wn + 16 * j + lm) * 32 + lk];
#pragma unroll
        for (int i = 0; i < 4; ++i)
#pragma unroll
            for (int j = 0; j < 4; ++j)
                acc[i][j] = __builtin_amdgcn_mfma_f32_16x16x32_bf16(a[i], b[j], acc[i][j], 0, 0, 0);
    }

    float bv[4];
#pragma unroll
    for (int j = 0; j < 4; ++j) bv[j] = bias[n0 + 64 * wn + 16 * j + lm];
#pragma unroll
    for (int i = 0; i < 4; ++i)
#pragma unroll
        for (int reg = 0; reg < 4; ++reg) {
            const int row = m0 + 64 * wm + 16 * i + 4 * (lane >> 4) + reg;
#pragma unroll
            for (int j = 0; j < 4; ++j) {
                const int col = n0 + 64 * wn + 16 * j + lm;
                const float v = acc[i][j][reg] + bv[j];
                if (BF16OUT) ((unsigned short*)Cout)[(size_t)row * N + col] = f2bf(v);
                else         ((float*)Cout)[(size_t)row * N + col] = v;
            }
        }
}

// ---------------------------------------------------------------------------
// Flash attention v2: 32x32x16 MFMA, transpose trick, no P LDS round-trip.
// Br=128 (4 waves x 32 q), Bc=64.  LDS: K 16KB + Vt 16KB (reused at epilogue).
// St = K*Q^T  (A=K-frag from LDS, B=Q-frag hoisted in regs)  -> col=q layout
// Ot = V*P^T  (A=V-frag from LDS, B=P-frag via 2 shfl_xor/kstep) -> col=q
// All LDS tiles 16B-chunk XOR swizzled; bank loads verified balanced.
// ---------------------------------------------------------------------------
__global__ __launch_bounds__(256, 2) void attn_mfma2(
    const unsigned short* __restrict__ Q,   // [4096][2048] bf16
    const unsigned short* __restrict__ Kg_, // [2,4,2048,128] bf16
    const unsigned short* __restrict__ Vt,  // [2,4,128,2048] bf16
    unsigned short* __restrict__ O)         // [4096][2048] bf16
{
    __shared__ __align__(16) unsigned short Ks[64 * 128];  // [key][16 chunks]
    __shared__ __align__(16) unsigned short Vs[128 * 64];  // [d][8 chunks]

    const int tid = threadIdx.x, lane = tid & 63, w = tid >> 6;
    const int h2 = lane >> 5;          // k-group half
    const int ln = lane & 31;          // q column (St/Ot) / key row (A) / d row (A)

    // pair heavy+light q-blocks on the same CU: bids i and i+256 -> qb sum 15
    const int bid = blockIdx.x;
    const int jj = bid >> 5;
    const int qb = (jj < 8) ? (15 - jj) : (jj - 8);
    const int bh = bid & 31;
    const int s0 = qb * 128;
    const int b = bh >> 4, h = bh & 15, kh = h >> 2;

    const unsigned short* Kb = Kg_ + (size_t)(b * 4 + kh) * 2048 * 128;
    const unsigned short* Vg = Vt + (size_t)(b * 4 + kh) * 128 * 2048;

    // ---- hoist Q fragments: B[n=q=ln][k=16ks+8h2+j] ----
    const int qg = s0 + 32 * w + ln;   // this lane's q row (both halves same q)
    const unsigned short* Qp = Q + (size_t)(b * 2048 + qg) * 2048 + h * 128 + h2 * 8;
    short8 Qreg[8];
#pragma unroll
    for (int ks = 0; ks < 8; ++ks) Qreg[ks] = *(const short8*)(Qp + ks * 16);

    f32x16 Ot[4];
#pragma unroll
    for (int mt = 0; mt < 4; ++mt)
#pragma unroll
        for (int r = 0; r < 16; ++r) Ot[mt][r] = 0.f;
    float m_ = -INFINITY, l_ = 0.f;

    const int tmax = s0 + 64;
    for (int t0 = 0; t0 <= tmax; t0 += 64) {
        __syncthreads();   // prev iter K/V reads done
        // ---- stage K tile [key][d], swizzle chunk c ^ (key&15) ----
#pragma unroll
        for (int p = 0; p < 4; ++p) {
            const int f = p * 256 + tid, r = f >> 4, c = f & 15;
            const short8 v = *(const short8*)(Kb + (size_t)(t0 + r) * 128 + c * 8);
            *(short8*)&Ks[(r * 16 + (c ^ (r & 15))) * 8] = v;
        }
        // ---- stage Vt tile [d][key], swizzle chunk c ^ (d&7) ----
#pragma unroll
        for (int p = 0; p < 4; ++p) {
            const int f = p * 256 + tid, d = f >> 3, c = f & 7;
            const short8 v = *(const short8*)(Vg + (size_t)d * 2048 + t0 + c * 8);
            *(short8*)&Vs[(d * 8 + (c ^ (d & 7))) * 8] = v;
        }
        __syncthreads();

        if (t0 <= s0 + 32 * w + 31) {   // wave has >=1 unmasked column
            // ---- St = K Q^T : col=q=ln, rows=key ----
            f32x16 St[2];
#pragma unroll
            for (int kt = 0; kt < 2; ++kt)
#pragma unroll
                for (int r = 0; r < 16; ++r) St[kt][r] = 0.f;
#pragma unroll
            for (int ks = 0; ks < 8; ++ks)
#pragma unroll
                for (int kt = 0; kt < 2; ++kt) {
                    const int key = 32 * kt + ln;
                    const int ch = (2 * ks + h2) ^ (key & 15);
                    const short8 a = *(const short8*)&Ks[(key * 16 + ch) * 8];
                    St[kt] = __builtin_amdgcn_mfma_f32_32x32x16_bf16(a, Qreg[ks], St[kt], 0, 0, 0);
                }

            // ---- mask + scale, in-place; lane-local row max (col q fixed) ----
            float mx = -INFINITY;
#pragma unroll
            for (int kt = 0; kt < 2; ++kt)
#pragma unroll
                for (int r = 0; r < 16; ++r) {
                    const int key = t0 + 32 * kt + (r & 3) + 8 * (r >> 2) + 4 * h2;
                    const float v = (key <= qg) ? St[kt][r] * RSQ128 : MASK6;
                    St[kt][r] = v;
                    mx = fmaxf(mx, v);
                }
            mx = fmaxf(mx, __shfl_xor(mx, 32));
            const float mn = fmaxf(m_, mx);
            const float alpha = __expf(m_ - mn);   // 0 on first tile
            m_ = mn;

            // ---- P = exp(s-m), pack bf16 pairs; row sum ----
            float s_loc = 0.f;
            unsigned Pp[16];
#pragma unroll
            for (int kt = 0; kt < 2; ++kt)
#pragma unroll
                for (int p = 0; p < 8; ++p) {
                    const float p0 = __expf(St[kt][2 * p] - mn);
                    const float p1 = __expf(St[kt][2 * p + 1] - mn);
                    s_loc += p0 + p1;
                    Pp[kt * 8 + p] = (unsigned)f2bf(p0) | ((unsigned)f2bf(p1) << 16);
                }
            s_loc += __shfl_xor(s_loc, 32);
            l_ = l_ * alpha + s_loc;
#pragma unroll
            for (int mt = 0; mt < 4; ++mt)
#pragma unroll
                for (int r = 0; r < 16; ++r) Ot[mt][r] *= alpha;

            // ---- Ot += V P^T ----
#pragma unroll
            for (int ks4 = 0; ks4 < 4; ++ks4) {
                const int base = (ks4 >> 1) * 8 + 4 * (ks4 & 1);
                const unsigned pa = Pp[base + 0], pb = Pp[base + 1];
                const unsigned pc = Pp[base + 2], pd = Pp[base + 3];
                // lower needs upper's (pa,pb); upper needs lower's (pc,pd)
                const unsigned x0 = (unsigned)__shfl_xor((int)(h2 ? pa : pc), 32);
                const unsigned x1 = (unsigned)__shfl_xor((int)(h2 ? pb : pd), 32);
                union { unsigned u[4]; short8 s8; } fr;
                fr.u[0] = h2 ? x0 : pa;
                fr.u[1] = h2 ? x1 : pb;
                fr.u[2] = h2 ? pc : x0;
                fr.u[3] = h2 ? pd : x1;
#pragma unroll
                for (int mt = 0; mt < 4; ++mt) {
                    const int d = 32 * mt + ln;
                    const int ch = (2 * ks4 + h2) ^ (d & 7);
                    const short8 a = *(const short8*)&Vs[(d * 8 + ch) * 8];
                    Ot[mt] = __builtin_amdgcn_mfma_f32_32x32x16_bf16(a, fr.s8, Ot[mt], 0, 0, 0);
                }
            }
        }
    }

    // ---- epilogue: transpose Ot/l through per-wave LDS, coalesced store ----
    __syncthreads();   // staging region reads complete in all waves
    unsigned short* Es = ((w & 2) ? Vs : Ks) + (w & 1) * 4096;  // 32q x 128d
    const float inv = 1.0f / l_;
#pragma unroll
    for (int mt = 0; mt < 4; ++mt)
#pragma unroll
        for (int r = 0; r < 16; ++r) {
            const int d = 32 * mt + (r & 3) + 8 * (r >> 2) + 4 * h2;
            Es[ln * 128 + (((d >> 3) ^ (ln & 15)) * 8) + (d & 7)] = f2bf(Ot[mt][r] * inv);
        }
    __syncthreads();
#pragma unroll
    for (int pp = 0; pp < 8; ++pp) {
        const int f = pp * 64 + lane;
        const int q = f >> 4, c = f & 15;
        const short8 v = *(const short8*)&Es[q * 128 + ((c ^ (q & 15)) * 8)];
        *(short8*)(O + (size_t)(b * 2048 + s0 + 32 * w + q) * 2048 + h * 128 + c * 8) = v;
    }
}

// ---------------------------------------------------------------------------
extern "C" void kernel_launch(void* const* d_in, const int* in_sizes, int n_in,
                              void* d_out, int out_size, void* d_ws, size_t ws_size,
                              hipStream_t stream) {
    const float* hs = (const float*)d_in[0];
    const float* k  = (const float*)d_in[1];
    const float* v  = (const float*)d_in[2];
    const float* wq = (const float*)d_in[3];
    const float* bq = (const float*)d_in[4];
    const float* wp = (const float*)d_in[5];
    const float* bp = (const float*)d_in[6];
    float* out = (float*)d_out;

    unsigned short* hsb  = (unsigned short*)d_ws;     // 8,388,608
    unsigned short* wqb  = hsb  + 8388608;            // 4,194,304
    unsigned short* kb   = wqb  + 4194304;            // 2,097,152
    unsigned short* vtb  = kb   + 2097152;            // 2,097,152
    unsigned short* qbuf = vtb  + 2097152;            // 8,388,608
    unsigned short* abuf = qbuf + 8388608;            // 8,388,608
    unsigned short* wpb  = hsb;                       // alias (hs dead after GEMM1)

    cvt_bf16<<<4096, 256, 0, stream>>>(hs, hsb);
    cvt_bf16<<<2048, 256, 0, stream>>>(wq, wqb);
    cvt_bf16<<<1024, 256, 0, stream>>>(k, kb);
    vtrans_bf16<<<dim3(32, 2, 8), 256, 0, stream>>>(v, vtb);

    dim3 gG(16, 32);
    gemm_nt_mfma<true><<<gG, 256, 0, stream>>>(hsb, wqb, bq, qbuf, 4096, 2048, 2048);
    cvt_bf16<<<2048, 256, 0, stream>>>(wp, wpb);
    attn_mfma2<<<512, 256, 0, stream>>>(qbuf, kb, vtb, abuf);
    gemm_nt_mfma<false><<<gG, 256, 0, stream>>>(abuf, wpb, bp, out, 4096, 2048, 2048);
}

// Round 4
// 318.582 us; speedup vs baseline: 1.1208x; 1.1208x over previous
//
#include <hip/hip_runtime.h>
#include <math.h>

// B=2, S=2048, H=2048, NH=16, KVH=4, D=128, layer 5.
// GEMMs on mfma_f32_16x16x32_bf16; attention on mfma_f32_32x32x16_bf16.
// valid logit = qk / sqrt(128); masked logit = -65504*6 (finite, exp -> 0).

#define RSQ128 0.08838834764831845f
#define MASK6  (-393024.0f)

typedef __attribute__((ext_vector_type(8))) short short8;    // 8 bf16 = 4 VGPR
typedef __attribute__((ext_vector_type(4))) float f32x4;     // 16x16 C/D
typedef __attribute__((ext_vector_type(16))) float f32x16;   // 32x32 C/D

static __device__ __forceinline__ unsigned short f2bf(float x) {
    union { float f; unsigned u; } v; v.f = x;
    unsigned r = v.u + 0x7FFFu + ((v.u >> 16) & 1u);   // RNE
    return (unsigned short)(r >> 16);
}

static __device__ __forceinline__ void gl_lds16(const void* g, void* l) {
    __builtin_amdgcn_global_load_lds(
        (const __attribute__((address_space(1))) void*)g,
        (__attribute__((address_space(3))) void*)l, 16, 0, 0);
}

// ---------------------------------------------------------------------------
// fp32 -> bf16 convert, 8 elems/thread
// ---------------------------------------------------------------------------
__global__ void cvt_bf16(const float* __restrict__ in, unsigned short* __restrict__ out) {
    const int i = (blockIdx.x * 256 + threadIdx.x) * 8;
    const float4 a = *(const float4*)(in + i);
    const float4 b = *(const float4*)(in + i + 4);
    short8 o;
    o[0] = (short)f2bf(a.x); o[1] = (short)f2bf(a.y);
    o[2] = (short)f2bf(a.z); o[3] = (short)f2bf(a.w);
    o[4] = (short)f2bf(b.x); o[5] = (short)f2bf(b.y);
    o[6] = (short)f2bf(b.z); o[7] = (short)f2bf(b.w);
    *(short8*)(out + i) = o;
}

// ---------------------------------------------------------------------------
// V [8][2048][128] fp32 -> Vt [8][128][2048] bf16 (per (b,kvh) transpose)
// ---------------------------------------------------------------------------
__global__ void vtrans_bf16(const float* __restrict__ V, unsigned short* __restrict__ Vt) {
    __shared__ float Ts[64][65];
    const int t = threadIdx.x;
    const int s0 = blockIdx.x * 64, d0 = blockIdx.y * 64;
    const float* src = V + (size_t)blockIdx.z * 2048 * 128;
    unsigned short* dst = Vt + (size_t)blockIdx.z * 128 * 2048;
#pragma unroll
    for (int p = 0; p < 4; ++p) {
        const int f = p * 256 + t, r = f >> 4, cq = f & 15;
        const float4 v = *(const float4*)(src + (size_t)(s0 + r) * 128 + d0 + cq * 4);
        Ts[r][cq * 4 + 0] = v.x; Ts[r][cq * 4 + 1] = v.y;
        Ts[r][cq * 4 + 2] = v.z; Ts[r][cq * 4 + 3] = v.w;
    }
    __syncthreads();
#pragma unroll
    for (int p = 0; p < 2; ++p) {
        const int f = p * 256 + t, dr = f >> 3, c = f & 7;
        short8 o;
#pragma unroll
        for (int j = 0; j < 8; ++j) o[j] = (short)f2bf(Ts[c * 8 + j][dr]);
        *(short8*)(dst + (size_t)(d0 + dr) * 2048 + s0 + c * 8) = o;
    }
}

// ---------------------------------------------------------------------------
// NT GEMM bf16 MFMA (unchanged — known good)
// ---------------------------------------------------------------------------
template <bool BF16OUT>
__global__ __launch_bounds__(256, 2) void gemm_nt_mfma(
    const unsigned short* __restrict__ A,
    const unsigned short* __restrict__ W,
    const float* __restrict__ bias,
    void* __restrict__ Cout, int M, int N, int K)
{
    __shared__ __align__(16) unsigned short As[128 * 32];
    __shared__ __align__(16) unsigned short Ws[128 * 32];
    const int tid = threadIdx.x, lane = tid & 63, w = tid >> 6;
    const int wm = w & 1, wn = w >> 1;
    const int m0 = blockIdx.y * 128, n0 = blockIdx.x * 128;
    const int r0 = tid >> 2, c0 = tid & 3;

    const unsigned short* Ag = A + (size_t)(m0 + r0) * K + c0 * 8;
    const unsigned short* Wg = W + (size_t)(n0 + r0) * K + c0 * 8;

    f32x4 acc[4][4];
#pragma unroll
    for (int i = 0; i < 4; ++i)
#pragma unroll
        for (int j = 0; j < 4; ++j) acc[i][j] = (f32x4){0.f, 0.f, 0.f, 0.f};

    const int lm = lane & 15, lk = (lane >> 4) * 8;

    for (int k0 = 0; k0 < K; k0 += 32) {
        __syncthreads();
        gl_lds16(Ag + k0,                  As + tid * 8);
        gl_lds16(Ag + (size_t)64 * K + k0, As + (tid + 256) * 8);
        gl_lds16(Wg + k0,                  Ws + tid * 8);
        gl_lds16(Wg + (size_t)64 * K + k0, Ws + (tid + 256) * 8);
        __syncthreads();

        short8 a[4], b[4];
#pragma unroll
        for (int i = 0; i < 4; ++i)
            a[i] = *(const short8*)&As[(64 * wm + 16 * i + lm) * 32 + lk];
#pragma unroll
        for (int j = 0; j < 4; ++j)
            b[j] = *(const short8*)&Ws[(64 * wn + 16 * j + lm) * 32 + lk];
#pragma unroll
        for (int i = 0; i < 4; ++i)
#pragma unroll
            for (int j = 0; j < 4; ++j)
                acc[i][j] = __builtin_amdgcn_mfma_f32_16x16x32_bf16(a[i], b[j], acc[i][j], 0, 0, 0);
    }

    float bv[4];
#pragma unroll
    for (int j = 0; j < 4; ++j) bv[j] = bias[n0 + 64 * wn + 16 * j + lm];
#pragma unroll
    for (int i = 0; i < 4; ++i)
#pragma unroll
        for (int reg = 0; reg < 4; ++reg) {
            const int row = m0 + 64 * wm + 16 * i + 4 * (lane >> 4) + reg;
#pragma unroll
            for (int j = 0; j < 4; ++j) {
                const int col = n0 + 64 * wn + 16 * j + lm;
                const float v = acc[i][j][reg] + bv[j];
                if (BF16OUT) ((unsigned short*)Cout)[(size_t)row * N + col] = f2bf(v);
                else         ((float*)Cout)[(size_t)row * N + col] = v;
            }
        }
}

// ---------------------------------------------------------------------------
// Flash attention v3: 32x32x16 MFMA, transpose trick, 2-wave blocks (Br=64).
// Grid 1024 blocks, 32KB LDS -> ~5 blocks/CU residency (vs R3's 2).
// St = K*Q^T (A=K from LDS, B=Q hoisted); Ot = V*P^T (P via 2 shfl/kstep).
// Block->qb mapping: constant work-sum per CU stride-256 set.
// ---------------------------------------------------------------------------
__global__ __launch_bounds__(128, 4) void attn_mfma3(
    const unsigned short* __restrict__ Q,   // [4096][2048] bf16
    const unsigned short* __restrict__ Kg_, // [2,4,2048,128] bf16
    const unsigned short* __restrict__ Vt,  // [2,4,128,2048] bf16
    unsigned short* __restrict__ O)         // [4096][2048] bf16
{
    __shared__ __align__(16) unsigned short Ks[64 * 128];  // [key][16 chunks]
    __shared__ __align__(16) unsigned short Vs[128 * 64];  // [d][8 chunks]

    const int tid = threadIdx.x, lane = tid & 63, w = tid >> 6;  // w in {0,1}
    const int h2 = lane >> 5;
    const int ln = lane & 31;

    // qb permutation: CU's stride-256 block set has constant total work
    const int bid = blockIdx.x;
    const int jj = bid >> 5;                 // 0..31
    const int aa = jj & 7, bb = jj >> 3;     // a 0..7, b 0..3
    const int qb = 8 * bb + ((bb & 1) ? (7 - aa) : aa);
    const int bh = bid & 31;
    const int s0 = qb * 64;
    const int b = bh >> 4, h = bh & 15, kh = h >> 2;

    const unsigned short* Kb = Kg_ + (size_t)(b * 4 + kh) * 2048 * 128;
    const unsigned short* Vg = Vt + (size_t)(b * 4 + kh) * 128 * 2048;

    // ---- hoist Q fragments: B[n=q=ln][k=16ks+8h2+j] ----
    const int qg = s0 + 32 * w + ln;
    const unsigned short* Qp = Q + (size_t)(b * 2048 + qg) * 2048 + h * 128 + h2 * 8;
    short8 Qreg[8];
#pragma unroll
    for (int ks = 0; ks < 8; ++ks) Qreg[ks] = *(const short8*)(Qp + ks * 16);

    f32x16 Ot[4];
#pragma unroll
    for (int mt = 0; mt < 4; ++mt)
#pragma unroll
        for (int r = 0; r < 16; ++r) Ot[mt][r] = 0.f;
    float m_ = -INFINITY, l_ = 0.f;

    for (int t0 = 0; t0 <= s0; t0 += 64) {
        __syncthreads();   // prev iter K/V reads done
        // ---- stage K tile [key][d], swizzle chunk c ^ (key&15) ----
#pragma unroll
        for (int p = 0; p < 8; ++p) {
            const int f = p * 128 + tid, r = f >> 4, c = f & 15;
            const short8 v = *(const short8*)(Kb + (size_t)(t0 + r) * 128 + c * 8);
            *(short8*)&Ks[(r * 16 + (c ^ (r & 15))) * 8] = v;
        }
        // ---- stage Vt tile [d][key], swizzle chunk c ^ (d&7) ----
#pragma unroll
        for (int p = 0; p < 8; ++p) {
            const int f = p * 128 + tid, d = f >> 3, c = f & 7;
            const short8 v = *(const short8*)(Vg + (size_t)d * 2048 + t0 + c * 8);
            *(short8*)&Vs[(d * 8 + (c ^ (d & 7))) * 8] = v;
        }
        __syncthreads();

        // ---- St = K Q^T : col=q=ln, rows=key ----
        f32x16 St[2];
#pragma unroll
        for (int kt = 0; kt < 2; ++kt)
#pragma unroll
            for (int r = 0; r < 16; ++r) St[kt][r] = 0.f;
#pragma unroll
        for (int ks = 0; ks < 8; ++ks)
#pragma unroll
            for (int kt = 0; kt < 2; ++kt) {
                const int key = 32 * kt + ln;
                const int ch = (2 * ks + h2) ^ (key & 15);
                const short8 a = *(const short8*)&Ks[(key * 16 + ch) * 8];
                St[kt] = __builtin_amdgcn_mfma_f32_32x32x16_bf16(a, Qreg[ks], St[kt], 0, 0, 0);
            }

        // ---- mask + scale (fast path when wave fully unmasked); row max ----
        float mx = -INFINITY;
        if (t0 + 63 <= s0 + 32 * w) {     // all keys <= all q rows of this wave
#pragma unroll
            for (int kt = 0; kt < 2; ++kt)
#pragma unroll
                for (int r = 0; r < 16; ++r) {
                    const float v = St[kt][r] * RSQ128;
                    St[kt][r] = v;
                    mx = fmaxf(mx, v);
                }
        } else {
#pragma unroll
            for (int kt = 0; kt < 2; ++kt)
#pragma unroll
                for (int r = 0; r < 16; ++r) {
                    const int key = t0 + 32 * kt + (r & 3) + 8 * (r >> 2) + 4 * h2;
                    const float v = (key <= qg) ? St[kt][r] * RSQ128 : MASK6;
                    St[kt][r] = v;
                    mx = fmaxf(mx, v);
                }
        }
        mx = fmaxf(mx, __shfl_xor(mx, 32));
        const float mn = fmaxf(m_, mx);
        float alpha = 1.f;
        if (__any(mx > m_)) {
            alpha = __expf(m_ - mn);      // 0 on first tile
#pragma unroll
            for (int mt = 0; mt < 4; ++mt)
#pragma unroll
                for (int r = 0; r < 16; ++r) Ot[mt][r] *= alpha;
        }
        m_ = mn;

        // ---- P = exp(s-m), pack bf16 pairs; row sum ----
        float s_loc = 0.f;
        unsigned Pp[16];
#pragma unroll
        for (int kt = 0; kt < 2; ++kt)
#pragma unroll
            for (int p = 0; p < 8; ++p) {
                const float p0 = __expf(St[kt][2 * p] - mn);
                const float p1 = __expf(St[kt][2 * p + 1] - mn);
                s_loc += p0 + p1;
                Pp[kt * 8 + p] = (unsigned)f2bf(p0) | ((unsigned)f2bf(p1) << 16);
            }
        s_loc += __shfl_xor(s_loc, 32);
        l_ = l_ * alpha + s_loc;

        // ---- Ot += V P^T ----
#pragma unroll
        for (int ks4 = 0; ks4 < 4; ++ks4) {
            const int base = (ks4 >> 1) * 8 + 4 * (ks4 & 1);
            const unsigned pa = Pp[base + 0], pb = Pp[base + 1];
            const unsigned pc = Pp[base + 2], pd = Pp[base + 3];
            const unsigned x0 = (unsigned)__shfl_xor((int)(h2 ? pa : pc), 32);
            const unsigned x1 = (unsigned)__shfl_xor((int)(h2 ? pb : pd), 32);
            union { unsigned u[4]; short8 s8; } fr;
            fr.u[0] = h2 ? x0 : pa;
            fr.u[1] = h2 ? x1 : pb;
            fr.u[2] = h2 ? pc : x0;
            fr.u[3] = h2 ? pd : x1;
#pragma unroll
            for (int mt = 0; mt < 4; ++mt) {
                const int d = 32 * mt + ln;
                const int ch = (2 * ks4 + h2) ^ (d & 7);
                const short8 a = *(const short8*)&Vs[(d * 8 + ch) * 8];
                Ot[mt] = __builtin_amdgcn_mfma_f32_32x32x16_bf16(a, fr.s8, Ot[mt], 0, 0, 0);
            }
        }
    }

    // ---- epilogue: transpose Ot/l via LDS (b64 packs), coalesced store ----
    __syncthreads();   // both waves done with Ks/Vs
    unsigned short* Es = Ks + w * 4096;   // 32q x 128d per wave
    const float inv = 1.0f / l_;
#pragma unroll
    for (int mt = 0; mt < 4; ++mt)
#pragma unroll
        for (int g = 0; g < 4; ++g) {
            short4 pk;
            pk.x = (short)f2bf(Ot[mt][4 * g + 0] * inv);
            pk.y = (short)f2bf(Ot[mt][4 * g + 1] * inv);
            pk.z = (short)f2bf(Ot[mt][4 * g + 2] * inv);
            pk.w = (short)f2bf(Ot[mt][4 * g + 3] * inv);
            const int chunk = (4 * mt + g) ^ (ln & 15);
            *(short4*)&Es[ln * 128 + chunk * 8 + 4 * h2] = pk;
        }
    __syncthreads();
#pragma unroll
    for (int pp = 0; pp < 8; ++pp) {
        const int f = pp * 64 + lane;
        const int q = f >> 4, c = f & 15;
        const short8 v = *(const short8*)&Es[q * 128 + ((c ^ (q & 15)) * 8)];
        *(short8*)(O + (size_t)(b * 2048 + s0 + 32 * w + q) * 2048 + h * 128 + c * 8) = v;
    }
}

// ---------------------------------------------------------------------------
extern "C" void kernel_launch(void* const* d_in, const int* in_sizes, int n_in,
                              void* d_out, int out_size, void* d_ws, size_t ws_size,
                              hipStream_t stream) {
    const float* hs = (const float*)d_in[0];
    const float* k  = (const float*)d_in[1];
    const float* v  = (const float*)d_in[2];
    const float* wq = (const float*)d_in[3];
    const float* bq = (const float*)d_in[4];
    const float* wp = (const float*)d_in[5];
    const float* bp = (const float*)d_in[6];
    float* out = (float*)d_out;

    unsigned short* hsb  = (unsigned short*)d_ws;     // 8,388,608
    unsigned short* wqb  = hsb  + 8388608;            // 4,194,304
    unsigned short* kb   = wqb  + 4194304;            // 2,097,152
    unsigned short* vtb  = kb   + 2097152;            // 2,097,152
    unsigned short* qbuf = vtb  + 2097152;            // 8,388,608
    unsigned short* abuf = qbuf + 8388608;            // 8,388,608
    unsigned short* wpb  = hsb;                       // alias (hs dead after GEMM1)

    cvt_bf16<<<4096, 256, 0, stream>>>(hs, hsb);
    cvt_bf16<<<2048, 256, 0, stream>>>(wq, wqb);
    cvt_bf16<<<1024, 256, 0, stream>>>(k, kb);
    vtrans_bf16<<<dim3(32, 2, 8), 256, 0, stream>>>(v, vtb);

    dim3 gG(16, 32);
    gemm_nt_mfma<true><<<gG, 256, 0, stream>>>(hsb, wqb, bq, qbuf, 4096, 2048, 2048);
    cvt_bf16<<<2048, 256, 0, stream>>>(wp, wpb);
    attn_mfma3<<<1024, 128, 0, stream>>>(qbuf, kb, vtb, abuf);
    gemm_nt_mfma<false><<<gG, 256, 0, stream>>>(abuf, wpb, bp, out, 4096, 2048, 2048);
}